// Round 3
// baseline (716.742 us; speedup 1.0000x reference)
//
#include <hip/hip_runtime.h>
#include <hip/hip_cooperative_groups.h>
#include <cfloat>

namespace cg = cooperative_groups;

// Problem constants
#define B_    256
#define S_    512
#define H_    768
#define LLEFT 256
#define LT    64
#define OUTD  3

// ---------------------------------------------------------------------------
// Device helpers
// ---------------------------------------------------------------------------
__device__ __forceinline__
void gemm_tile_splitk(const float* __restrict__ A,   // [M,K]
                      const float* __restrict__ W,   // [K,N]
                      float* __restrict__ P,         // [SK,M,N]
                      int M, int N, int K,
                      int ntilesx, int SK,
                      int blk, int tid,
                      float (*As)[68], float (*Bs)[64])
{
    const int ntiles  = ntilesx * (M / 64);
    const int nactive = ntiles * SK;
    if (blk >= nactive) return;

    const int z     = blk / ntiles;
    const int tile  = blk % ntiles;
    const int nbase = (tile % ntilesx) * 64;
    const int mbase = (tile / ntilesx) * 64;
    const int Kper  = K / SK;
    const int kbeg  = z * Kper;

    const int trow = tid / 16;         // 0..15
    const int tcol = tid % 16;         // 0..15
    const int a_m  = tid >> 2;         // 0..63
    const int a_k  = (tid & 3) * 4;    // 0,4,8,12
    const int b_k  = tid >> 4;         // 0..15
    const int b_n  = (tid & 15) * 4;   // 0..60

    float acc[4][4] = {};

    for (int k0 = kbeg; k0 < kbeg + Kper; k0 += 16) {
        const float4 a4 = *(const float4*)(A + (size_t)(mbase + a_m) * K + k0 + a_k);
        As[a_k + 0][a_m] = a4.x;
        As[a_k + 1][a_m] = a4.y;
        As[a_k + 2][a_m] = a4.z;
        As[a_k + 3][a_m] = a4.w;
        *(float4*)&Bs[b_k][b_n] = *(const float4*)(W + (size_t)(k0 + b_k) * N + nbase + b_n);
        __syncthreads();

#pragma unroll
        for (int k = 0; k < 16; ++k) {
            const float4 av = *(const float4*)&As[k][trow * 4];
            const float4 bv = *(const float4*)&Bs[k][tcol * 4];
            const float a[4] = {av.x, av.y, av.z, av.w};
            const float b[4] = {bv.x, bv.y, bv.z, bv.w};
#pragma unroll
            for (int i = 0; i < 4; ++i)
#pragma unroll
                for (int j = 0; j < 4; ++j)
                    acc[i][j] += a[i] * b[j];
        }
        __syncthreads();
    }

    float* Pb = P + (size_t)z * M * N;
#pragma unroll
    for (int i = 0; i < 4; ++i) {
        const int m = mbase + trow * 4 + i;
        const int n = nbase + tcol * 4;
        *(float4*)(Pb + (size_t)m * N + n) =
            make_float4(acc[i][0], acc[i][1], acc[i][2], acc[i][3]);
    }
}

__device__ __forceinline__
void reduce_bias_tanh(const float* __restrict__ P,
                      const float* __restrict__ bias,
                      float* __restrict__ C,
                      int MN, int N, int SK, int blk, int tid)
{
    const int idx = (blk * 256 + tid) * 4;
    if (idx >= MN) return;
    float4 v = *(const float4*)(P + idx);
    for (int s = 1; s < SK; ++s) {
        const float4 p = *(const float4*)(P + (size_t)s * MN + idx);
        v.x += p.x; v.y += p.y; v.z += p.z; v.w += p.w;
    }
    const int n = idx % N;
    v.x = tanhf(v.x + bias[n + 0]);
    v.y = tanhf(v.y + bias[n + 1]);
    v.z = tanhf(v.z + bias[n + 2]);
    v.w = tanhf(v.w + bias[n + 3]);
    *(float4*)(C + idx) = v;
}

// ---------------------------------------------------------------------------
// One cooperative kernel: pool -> L1 -> L2 -> L3 -> L4
// 256 blocks x 256 threads (1 block/CU), 6 grid syncs.
// ---------------------------------------------------------------------------
__global__ __launch_bounds__(256)
void fused_kernel(const float* __restrict__ SE,        // [B,S,H]
                  const float* __restrict__ pooled,    // [B,H]
                  const int* __restrict__ left_ids,    // [B,LLEFT]
                  const int* __restrict__ t_ids,       // [B,LT]
                  const float* __restrict__ W1, const float* __restrict__ b1,
                  const float* __restrict__ W2, const float* __restrict__ b2,
                  const float* __restrict__ W3, const float* __restrict__ b3,
                  const float* __restrict__ W4, const float* __restrict__ b4,
                  float* __restrict__ out,             // [B,OUT]
                  float* __restrict__ ws)
{
    cg::grid_group grid = cg::this_grid();

    __shared__ float As[16][68];
    __shared__ float Bs[16][64];
    __shared__ int   s_cnt[2];
    __shared__ float s_h3[H_ / 2];
    __shared__ float s_red[4][3];

    float* cat = ws;                       // B*1536
    float* h1  = cat + B_ * 2 * H_;        // B*768
    float* h2  = h1 + B_ * H_;             // B*768
    float* P   = h2 + B_ * H_;             // 786432 floats (max of both splits)

    const int blk = blockIdx.x;
    const int tid = threadIdx.x;

    // ---------------- phase 0: span max-pool + concat ----------------
    {
        const int b = blk;
        if (tid < 2) s_cnt[tid] = 0;
        __syncthreads();
        {
            unsigned long long m = __ballot(left_ids[b * LLEFT + tid] != 0);
            if ((tid & 63) == 0) atomicAdd(&s_cnt[0], __popcll(m));
        }
        if (tid < 64) {
            unsigned long long mt = __ballot(t_ids[b * LT + tid] != 0);
            if (tid == 0) s_cnt[1] = __popcll(mt);
        }
        __syncthreads();
        const int start = s_cnt[0] - 1;    // left_len
        const int len   = s_cnt[1] - 2;    // target_len >= 1

        if (tid < H_ / 4) {
            const float* se_b = SE + ((size_t)b * S_ + start) * H_;
            float4 m = make_float4(-FLT_MAX, -FLT_MAX, -FLT_MAX, -FLT_MAX);
            for (int r = 0; r < len; ++r) {
                const float4 v = *(const float4*)(se_b + (size_t)r * H_ + 4 * tid);
                m.x = fmaxf(m.x, v.x); m.y = fmaxf(m.y, v.y);
                m.z = fmaxf(m.z, v.z); m.w = fmaxf(m.w, v.w);
            }
            float* cb = cat + (size_t)b * (2 * H_);
            *(float4*)(cb + 4 * tid)      = *(const float4*)(pooled + (size_t)b * H_ + 4 * tid);
            *(float4*)(cb + H_ + 4 * tid) = m;
        }
    }
    grid.sync();

    // ---------------- layer 1: h1 = tanh(cat @ W1 + b1)  M=256 K=1536 N=768
    gemm_tile_splitk(cat, W1, P, B_, H_, 2 * H_, H_ / 64, 4, blk, tid, As, Bs);
    grid.sync();
    reduce_bias_tanh(P, b1, h1, B_ * H_, H_, 4, blk, tid);
    grid.sync();

    // ---------------- layer 2: h2 = tanh(h1 @ W2 + b2)   M=256 K=768 N=768
    gemm_tile_splitk(h1, W2, P, B_, H_, H_, H_ / 64, 4, blk, tid, As, Bs);
    grid.sync();
    reduce_bias_tanh(P, b2, h2, B_ * H_, H_, 4, blk, tid);
    grid.sync();

    // ---------------- layer 3 GEMM: P = h2 @ W3 (split-K 8)  M=256 K=768 N=384
    gemm_tile_splitk(h2, W3, P, B_, H_ / 2, H_, (H_ / 2) / 64, 8, blk, tid, As, Bs);
    grid.sync();

    // ---------------- fused: reduce3+bias+tanh (to LDS) + layer 4 dot ----
    {
        const int b = blk;
        constexpr int MN3 = B_ * (H_ / 2);
        if (tid < (H_ / 2) / 4) {
            const int off = b * (H_ / 2) + 4 * tid;
            float4 v = *(const float4*)(P + off);
            for (int s = 1; s < 8; ++s) {
                const float4 p = *(const float4*)(P + (size_t)s * MN3 + off);
                v.x += p.x; v.y += p.y; v.z += p.z; v.w += p.w;
            }
            v.x = tanhf(v.x + b3[4 * tid + 0]);
            v.y = tanhf(v.y + b3[4 * tid + 1]);
            v.z = tanhf(v.z + b3[4 * tid + 2]);
            v.w = tanhf(v.w + b3[4 * tid + 3]);
            *(float4*)&s_h3[4 * tid] = v;
        }
        __syncthreads();

        float a0 = 0.f, a1 = 0.f, a2 = 0.f;
        for (int k = tid; k < H_ / 2; k += 256) {
            const float h = s_h3[k];
            a0 += h * W4[k * OUTD + 0];
            a1 += h * W4[k * OUTD + 1];
            a2 += h * W4[k * OUTD + 2];
        }
#pragma unroll
        for (int off = 32; off; off >>= 1) {
            a0 += __shfl_down(a0, off);
            a1 += __shfl_down(a1, off);
            a2 += __shfl_down(a2, off);
        }
        if ((tid & 63) == 0) {
            const int w = tid >> 6;
            s_red[w][0] = a0; s_red[w][1] = a1; s_red[w][2] = a2;
        }
        __syncthreads();
        if (tid == 0) {
            float r0 = b4[0], r1 = b4[1], r2 = b4[2];
#pragma unroll
            for (int w = 0; w < 4; ++w) {
                r0 += s_red[w][0]; r1 += s_red[w][1]; r2 += s_red[w][2];
            }
            out[b * OUTD + 0] = r0;
            out[b * OUTD + 1] = r1;
            out[b * OUTD + 2] = r2;
        }
    }
}

// ---------------------------------------------------------------------------
extern "C" void kernel_launch(void* const* d_in, const int* in_sizes, int n_in,
                              void* d_out, int out_size, void* d_ws, size_t ws_size,
                              hipStream_t stream)
{
    const float* SE       = (const float*)d_in[0];
    const float* pooled   = (const float*)d_in[1];
    const int*   left_ids = (const int*)  d_in[2];
    const int*   t_ids    = (const int*)  d_in[3];
    const float* W1 = (const float*)d_in[4];
    const float* b1 = (const float*)d_in[5];
    const float* W2 = (const float*)d_in[6];
    const float* b2 = (const float*)d_in[7];
    const float* W3 = (const float*)d_in[8];
    const float* b3 = (const float*)d_in[9];
    const float* W4 = (const float*)d_in[10];
    const float* b4 = (const float*)d_in[11];
    float* out = (float*)d_out;
    float* ws  = (float*)d_ws;

    void* args[] = {
        (void*)&SE, (void*)&pooled, (void*)&left_ids, (void*)&t_ids,
        (void*)&W1, (void*)&b1, (void*)&W2, (void*)&b2,
        (void*)&W3, (void*)&b3, (void*)&W4, (void*)&b4,
        (void*)&out, (void*)&ws
    };
    hipLaunchCooperativeKernel((void*)fused_kernel, dim3(B_), dim3(256),
                               args, 0, stream);
}

// Round 4
// 509.288 us; speedup vs baseline: 1.4073x; 1.4073x over previous
//
#include <hip/hip_runtime.h>
#include <cfloat>

// Problem constants
#define B_    256
#define S_    512
#define H_    768
#define LLEFT 256
#define LT    64
#define OUTD  3

// ---------------------------------------------------------------------------
// Kernel 1: per-batch ragged span max-pool + concat [pooled | span_max]
// ---------------------------------------------------------------------------
__global__ __launch_bounds__(256)
void pool_cat_kernel(const float* __restrict__ SE,        // [B,S,H]
                     const float* __restrict__ pooled,    // [B,H]
                     const int* __restrict__ left_ids,    // [B,LLEFT]
                     const int* __restrict__ t_ids,       // [B,LT]
                     float* __restrict__ cat)             // [B,2H]
{
    const int b = blockIdx.x;
    const int t = threadIdx.x;

    __shared__ int s_cnt[2];
    if (t < 2) s_cnt[t] = 0;
    __syncthreads();

    {
        unsigned long long m = __ballot(left_ids[b * LLEFT + t] != 0);
        if ((t & 63) == 0) atomicAdd(&s_cnt[0], __popcll(m));
    }
    if (t < 64) {
        unsigned long long mt = __ballot(t_ids[b * LT + t] != 0);
        if (t == 0) s_cnt[1] = __popcll(mt);
    }
    __syncthreads();

    const int start = s_cnt[0] - 1;   // left_len
    const int len   = s_cnt[1] - 2;   // target_len >= 1

    if (t < H_ / 4) {
        const float* se_b = SE + ((size_t)b * S_ + start) * H_;
        float4 m = make_float4(-FLT_MAX, -FLT_MAX, -FLT_MAX, -FLT_MAX);
        for (int r = 0; r < len; ++r) {
            const float4 v = *(const float4*)(se_b + (size_t)r * H_ + 4 * t);
            m.x = fmaxf(m.x, v.x); m.y = fmaxf(m.y, v.y);
            m.z = fmaxf(m.z, v.z); m.w = fmaxf(m.w, v.w);
        }
        float* cb = cat + (size_t)b * (2 * H_);
        *(float4*)(cb + 4 * t)      = *(const float4*)(pooled + (size_t)b * H_ + 4 * t);
        *(float4*)(cb + H_ + 4 * t) = m;
    }
}

// ---------------------------------------------------------------------------
// Split-K tiled fp32 GEMM partial, compile-time shape: P[sk] = A[:,ksk]@W[ksk,:]
// BM=BN=64, BK=16, 256 threads, 4x4 micro-tile. grid = (N/64, M/64, SK).
// Kper = K/SK is small (32..96) -> K-loop fully unrolls.
// ---------------------------------------------------------------------------
template <int M, int N, int K, int SK>
__global__ __launch_bounds__(256)
void gemm_splitk(const float* __restrict__ A,
                 const float* __restrict__ W,
                 float* __restrict__ P)        // [SK, M, N]
{
    constexpr int BK = 16, Kper = K / SK;
    __shared__ float As[BK][68];
    __shared__ float Bs[BK][64];

    const int tid  = threadIdx.x;
    const int trow = tid / 16;         // 0..15
    const int tcol = tid % 16;         // 0..15
    const int mbase = blockIdx.y * 64;
    const int nbase = blockIdx.x * 64;
    const int kbeg  = blockIdx.z * Kper;

    const int a_m = tid >> 2;          // 0..63
    const int a_k = (tid & 3) * 4;     // 0,4,8,12
    const int b_k = tid >> 4;          // 0..15
    const int b_n = (tid & 15) * 4;    // 0..60

    float acc[4][4] = {};

#pragma unroll
    for (int ki = 0; ki < Kper / BK; ++ki) {
        const int k0 = kbeg + ki * BK;
        const float4 a4 = *(const float4*)(A + (size_t)(mbase + a_m) * K + k0 + a_k);
        As[a_k + 0][a_m] = a4.x;
        As[a_k + 1][a_m] = a4.y;
        As[a_k + 2][a_m] = a4.z;
        As[a_k + 3][a_m] = a4.w;
        *(float4*)&Bs[b_k][b_n] = *(const float4*)(W + (size_t)(k0 + b_k) * N + nbase + b_n);
        __syncthreads();

#pragma unroll
        for (int k = 0; k < BK; ++k) {
            const float4 av = *(const float4*)&As[k][trow * 4];
            const float4 bv = *(const float4*)&Bs[k][tcol * 4];
            const float a[4] = {av.x, av.y, av.z, av.w};
            const float b[4] = {bv.x, bv.y, bv.z, bv.w};
#pragma unroll
            for (int i = 0; i < 4; ++i)
#pragma unroll
                for (int j = 0; j < 4; ++j)
                    acc[i][j] += a[i] * b[j];
        }
        __syncthreads();
    }

    float* Pb = P + (size_t)blockIdx.z * M * N;
#pragma unroll
    for (int i = 0; i < 4; ++i) {
        const int m = mbase + trow * 4 + i;
        const int n = nbase + tcol * 4;
        *(float4*)(Pb + (size_t)m * N + n) =
            make_float4(acc[i][0], acc[i][1], acc[i][2], acc[i][3]);
    }
}

// ---------------------------------------------------------------------------
// Reduce over SK partials + bias + tanh. Elementwise over M*N, float4.
// ---------------------------------------------------------------------------
template <int MN, int N, int SK>
__global__ __launch_bounds__(256)
void reduce_bias_act(const float* __restrict__ P,
                     const float* __restrict__ bias,
                     float* __restrict__ C)
{
    const int idx = (blockIdx.x * 256 + threadIdx.x) * 4;
    if (idx >= MN) return;
    float4 v = *(const float4*)(P + idx);
#pragma unroll
    for (int s = 1; s < SK; ++s) {
        const float4 p = *(const float4*)(P + (size_t)s * MN + idx);
        v.x += p.x; v.y += p.y; v.z += p.z; v.w += p.w;
    }
    const int n = idx % N;
    v.x = tanhf(v.x + bias[n + 0]);
    v.y = tanhf(v.y + bias[n + 1]);
    v.z = tanhf(v.z + bias[n + 2]);
    v.w = tanhf(v.w + bias[n + 3]);
    *(float4*)(C + idx) = v;
}

// ---------------------------------------------------------------------------
// Final: reduce layer-3 partials + bias + tanh (LDS) then logits via W4.
// One block per batch sample.
// ---------------------------------------------------------------------------
template <int SK>
__global__ __launch_bounds__(256)
void reduce3_out_kernel(const float* __restrict__ P,    // [SK, B, H/2]
                        const float* __restrict__ b3,
                        const float* __restrict__ W4,   // [H/2, OUT]
                        const float* __restrict__ b4,
                        float* __restrict__ out)        // [B, OUT]
{
    constexpr int MN3 = B_ * (H_ / 2);
    const int b   = blockIdx.x;
    const int tid = threadIdx.x;

    __shared__ float s_h3[H_ / 2];
    __shared__ float s_red[4][3];

    if (tid < (H_ / 2) / 4) {
        const int off = b * (H_ / 2) + 4 * tid;
        float4 v = *(const float4*)(P + off);
#pragma unroll
        for (int s = 1; s < SK; ++s) {
            const float4 p = *(const float4*)(P + (size_t)s * MN3 + off);
            v.x += p.x; v.y += p.y; v.z += p.z; v.w += p.w;
        }
        v.x = tanhf(v.x + b3[4 * tid + 0]);
        v.y = tanhf(v.y + b3[4 * tid + 1]);
        v.z = tanhf(v.z + b3[4 * tid + 2]);
        v.w = tanhf(v.w + b3[4 * tid + 3]);
        *(float4*)&s_h3[4 * tid] = v;
    }
    __syncthreads();

    float a0 = 0.f, a1 = 0.f, a2 = 0.f;
    for (int k = tid; k < H_ / 2; k += 256) {
        const float h = s_h3[k];
        a0 += h * W4[k * OUTD + 0];
        a1 += h * W4[k * OUTD + 1];
        a2 += h * W4[k * OUTD + 2];
    }
#pragma unroll
    for (int off = 32; off; off >>= 1) {
        a0 += __shfl_down(a0, off);
        a1 += __shfl_down(a1, off);
        a2 += __shfl_down(a2, off);
    }
    if ((tid & 63) == 0) {
        const int w = tid >> 6;
        s_red[w][0] = a0; s_red[w][1] = a1; s_red[w][2] = a2;
    }
    __syncthreads();
    if (tid == 0) {
        float r0 = b4[0], r1 = b4[1], r2 = b4[2];
#pragma unroll
        for (int w = 0; w < 4; ++w) {
            r0 += s_red[w][0]; r1 += s_red[w][1]; r2 += s_red[w][2];
        }
        out[b * OUTD + 0] = r0;
        out[b * OUTD + 1] = r1;
        out[b * OUTD + 2] = r2;
    }
}

// ---------------------------------------------------------------------------
extern "C" void kernel_launch(void* const* d_in, const int* in_sizes, int n_in,
                              void* d_out, int out_size, void* d_ws, size_t ws_size,
                              hipStream_t stream)
{
    const float* SE       = (const float*)d_in[0];
    const float* pooled   = (const float*)d_in[1];
    const int*   left_ids = (const int*)  d_in[2];
    const int*   t_ids    = (const int*)  d_in[3];
    const float* W1 = (const float*)d_in[4];
    const float* b1 = (const float*)d_in[5];
    const float* W2 = (const float*)d_in[6];
    const float* b2 = (const float*)d_in[7];
    const float* W3 = (const float*)d_in[8];
    const float* b3 = (const float*)d_in[9];
    const float* W4 = (const float*)d_in[10];
    const float* b4 = (const float*)d_in[11];
    float* out = (float*)d_out;

    float* ws  = (float*)d_ws;
    float* cat = ws;                          // B*1536 = 393216
    float* h1  = cat + B_ * 2 * H_;           // B*768
    float* h2  = h1 + B_ * H_;                // B*768
    float* P   = h2 + B_ * H_;                // partials: max 16*256*768 = 3.1M floats

    constexpr int SK1 = 16, SK2 = 16, SK3 = 24;   // 768 / 768 / 576 blocks

    // 1) span max-pool + concat
    pool_cat_kernel<<<B_, 256, 0, stream>>>(SE, pooled, left_ids, t_ids, cat);

    // 2) h1 = tanh(cat @ W1 + b1)   M=256 K=1536 N=768
    gemm_splitk<B_, H_, 2 * H_, SK1>
        <<<dim3(H_ / 64, B_ / 64, SK1), 256, 0, stream>>>(cat, W1, P);
    reduce_bias_act<B_ * H_, H_, SK1>
        <<<(B_ * H_ / 4 + 255) / 256, 256, 0, stream>>>(P, b1, h1);

    // 3) h2 = tanh(h1 @ W2 + b2)    M=256 K=768 N=768
    gemm_splitk<B_, H_, H_, SK2>
        <<<dim3(H_ / 64, B_ / 64, SK2), 256, 0, stream>>>(h1, W2, P);
    reduce_bias_act<B_ * H_, H_, SK2>
        <<<(B_ * H_ / 4 + 255) / 256, 256, 0, stream>>>(P, b2, h2);

    // 4) h3 partials = h2 @ W3      M=256 K=768 N=384
    gemm_splitk<B_, H_ / 2, H_, SK3>
        <<<dim3((H_ / 2) / 64, B_ / 64, SK3), 256, 0, stream>>>(h2, W3, P);

    // 5) reduce3 + bias + tanh + layer4
    reduce3_out_kernel<SK3><<<B_, 256, 0, stream>>>(P, b3, W4, b4, out);
}